// Round 14
// baseline (99.874 us; speedup 1.0000x reference)
//
#include <hip/hip_runtime.h>
#include <hip/hip_bf16.h>
#include <cstddef>

// ---------------------------------------------------------------------------
// MORP: Lu = irfft( g(k) * rfft( h(u) ) ), h/g tiny MLPs (1->64->64->{1,2}, ELU)
// B=2048 rows, N=8192, M=4097, W=64.
// Round 14 = Round 13 (radix-8 512t, incremental swizzled addressing) +
//  (a) twiddle TABLE tw[j]=cis(-2pi j/4096) in ws (L2-hot): stage twiddles
//      become 7 loads + 7 cmuls (inverse = conj). Kills sincos + 13-cmul
//      product tree per stage (~37% of VALU insts).
//  (b) inverse-S3 writes DIRECTLY to global, coalesced, via digit-reverse
//      thread relabeling (qrev = m3 involution). Copy-out phase deleted.
//      S2->S3 handoff (both directions) uses swz3 = swz ^ ((i>>9)&7)
//      (per-thread-constant XOR) to keep that stage's reads bank-balanced.
// Out-of-place only (in-place BANNED). zres/v arrays fully unrolled (r10 rule).
// ---------------------------------------------------------------------------

#define TWO_PI_F 6.28318530717958647693f

struct __align__(8) cpx { float x, y; };

__device__ __forceinline__ cpx cmul(cpx a, cpx b) {
    return cpx{fmaf(a.x, b.x, -a.y * b.y), fmaf(a.x, b.y, a.y * b.x)};
}
__device__ __forceinline__ cpx cadd(cpx a, cpx b) { return cpx{a.x + b.x, a.y + b.y}; }
__device__ __forceinline__ cpx csub(cpx a, cpx b) { return cpx{a.x - b.x, a.y - b.y}; }
__device__ __forceinline__ cpx cscale(float s, cpx a) { return cpx{s * a.x, s * a.y}; }
__device__ __forceinline__ cpx cconj(cpx a) { return cpx{a.x, -a.y}; }
template <int S>
__device__ __forceinline__ cpx crot(cpx z) {   // multiply by S<0 ? -i : +i
    return (S < 0) ? cpx{z.y, -z.x} : cpx{-z.y, z.x};
}

__device__ __forceinline__ float elu(float x) {
    return x > 0.0f ? x : (__expf(x) - 1.0f);
}

// LDS index swizzle (bits 0-8 only; bits >=9 pass through untouched).
__device__ __forceinline__ int swz(int i) {
    return i ^ ((i >> 3) & 7) ^ (((i >> 6) & 7) << 1);
}

// ---------------------------------------------------------------------------
// In-register 4/8-point DFT (natural order), sign S (-1 fwd, +1 inv).
// ---------------------------------------------------------------------------
template <int S>
__device__ __forceinline__ void dft4(cpx& x0, cpx& x1, cpx& x2, cpx& x3) {
    cpx e0 = cadd(x0, x2), e1 = csub(x0, x2);
    cpx o0 = cadd(x1, x3), o1 = crot<S>(csub(x1, x3));
    x0 = cadd(e0, o0);
    x1 = cadd(e1, o1);
    x2 = csub(e0, o0);
    x3 = csub(e1, o1);
}

template <int S>
__device__ __forceinline__ void dft8(cpx v[8]) {
    constexpr float r = 0.70710678118654752f;
    cpx E0 = v[0], E1 = v[2], E2 = v[4], E3 = v[6];
    cpx O0 = v[1], O1 = v[3], O2 = v[5], O3 = v[7];
    dft4<S>(E0, E1, E2, E3);
    dft4<S>(O0, O1, O2, O3);
    O1 = (S < 0) ? cpx{r * (O1.x + O1.y), r * (O1.y - O1.x)}
                 : cpx{r * (O1.x - O1.y), r * (O1.x + O1.y)};
    O2 = crot<S>(O2);
    O3 = (S < 0) ? cpx{r * (O3.y - O3.x), -r * (O3.x + O3.y)}
                 : cpx{-r * (O3.x + O3.y), r * (O3.x - O3.y)};
    v[0] = cadd(E0, O0);
    v[1] = cadd(E1, O1);
    v[2] = cadd(E2, O2);
    v[3] = cadd(E3, O3);
    v[4] = csub(E0, O0);
    v[5] = csub(E1, O1);
    v[6] = csub(E2, O2);
    v[7] = csub(E3, O3);
}

// Apply tw[jb*t] (conj for S>0) to v[1..7]. jb*7 < 4096 for all call sites.
template <int S>
__device__ __forceinline__ void twid_apply(cpx v[8], const cpx* __restrict__ tw,
                                           int jb) {
    int j = jb;
#pragma unroll
    for (int t = 1; t < 8; ++t) {
        cpx w = tw[j];
        if constexpr (S > 0) w.y = -w.y;
        v[t] = cmul(v[t], w);
        j += jb;
    }
}

// ---------------------------------------------------------------------------
// Radix-8 stages (4096 = 8^4), 512 threads, out-of-place.
// ---------------------------------------------------------------------------
template <int S>
__device__ __forceinline__ void stage1(const cpx* __restrict__ src,
                                       cpx* __restrict__ dst, int s1, int jb,
                                       const cpx* __restrict__ tw) {
    cpx v[8];
#pragma unroll
    for (int t = 0; t < 8; ++t) v[t] = src[s1 ^ (66 * t)];
    if (jb) twid_apply<S>(v, tw, jb);    // jb wave-uniform here
    dft8<S>(v);
#pragma unroll
    for (int t = 0; t < 8; ++t) dst[s1 ^ (66 * t)] = v[t];
}

template <int S>
__device__ __forceinline__ void stage2(const cpx* __restrict__ src,
                                       cpx* __restrict__ dst, int s2r, int s2w,
                                       int jb, const cpx* __restrict__ tw) {
    cpx v[8];
#pragma unroll
    for (int t = 0; t < 8; ++t) v[t] = src[s2r ^ (9 * t)];
    twid_apply<S>(v, tw, jb);
    dft8<S>(v);
#pragma unroll
    for (int t = 0; t < 8; ++t) dst[s2w ^ (9 * t)] = v[t];
}

// forward S3: read swz3 layout, write bufB at swz(m3)+512t (old swz)
template <int S>
__device__ __forceinline__ void stage3(const cpx* __restrict__ src,
                                       cpx* __restrict__ dst, int s3r3, int s3w,
                                       int jb, const cpx* __restrict__ tw) {
    cpx v[8];
#pragma unroll
    for (int t = 0; t < 8; ++t) v[t] = src[s3r3 ^ t];
    twid_apply<S>(v, tw, jb);
    dft8<S>(v);
    cpx* __restrict__ pw = dst + s3w;
#pragma unroll
    for (int t = 0; t < 8; ++t) pw[512 * t] = v[t];
}

// ---------------------------------------------------------------------------
// Kernel 1: blocks 0..16 -> gk; 17..33 -> htab; 34..49 -> twiddle table.
// ---------------------------------------------------------------------------
__global__ __launch_bounds__(256, 2) void tables_kernel(
    const float* __restrict__ kin,
    const float* __restrict__ gw1, const float* __restrict__ gb1,
    const float* __restrict__ gw2, const float* __restrict__ gb2,
    const float* __restrict__ gw3, const float* __restrict__ gb3,
    const float* __restrict__ hw1, const float* __restrict__ hb1,
    const float* __restrict__ hw2, const float* __restrict__ hb2,
    const float* __restrict__ hw3, const float* __restrict__ hb3,
    cpx* __restrict__ gk_out, float* __restrict__ htab,
    cpx* __restrict__ twtab) {
    const int tid = threadIdx.x;
    if (blockIdx.x >= 34) {               // twiddle fill (uniform per block)
        const int j = (blockIdx.x - 34) * 256 + tid;
        float ang = -TWO_PI_F * (float)j / 4096.0f;
        cpx w;
        __sincosf(ang, &w.y, &w.x);
        twtab[j] = w;
        return;
    }
    __shared__ __align__(16) float w2[4096];
    __shared__ float w1[64], b1[64], b2[64], w3a[64], w3b[64];
    __shared__ float b3a, b3b;
    const bool isg = blockIdx.x < 17;
    const float* W1 = isg ? gw1 : hw1;
    const float* B1 = isg ? gb1 : hb1;
    const float* W2 = isg ? gw2 : hw2;
    const float* B2 = isg ? gb2 : hb2;
    for (int i = tid; i < 4096; i += 256) w2[i] = W2[i];
    if (tid < 64) {
        w1[tid] = W1[tid];
        b1[tid] = B1[tid];
        b2[tid] = B2[tid];
        if (isg) {
            w3a[tid] = gw3[tid * 2 + 0];
            w3b[tid] = gw3[tid * 2 + 1];
        } else {
            w3a[tid] = hw3[tid];
            w3b[tid] = 0.0f;
        }
    }
    if (tid == 0) {
        b3a = isg ? gb3[0] : hb3[0];
        b3b = isg ? gb3[1] : 0.0f;
    }
    __syncthreads();
    const int idx = (isg ? blockIdx.x : blockIdx.x - 17) * 256 + tid;
    if (idx >= 4097) return;
    const float x = isg ? kin[idx] : (-8.0f + (float)idx * (16.0f / 4096.0f));
    float acc[64];
#pragma unroll
    for (int i = 0; i < 64; ++i) acc[i] = b2[i];
#pragma unroll 2
    for (int j = 0; j < 64; ++j) {
        float h1 = elu(fmaf(x, w1[j], b1[j]));
        const float4* wr = (const float4*)&w2[j * 64];
#pragma unroll
        for (int q = 0; q < 16; ++q) {
            float4 wv = wr[q];
            acc[q * 4 + 0] = fmaf(h1, wv.x, acc[q * 4 + 0]);
            acc[q * 4 + 1] = fmaf(h1, wv.y, acc[q * 4 + 1]);
            acc[q * 4 + 2] = fmaf(h1, wv.z, acc[q * 4 + 2]);
            acc[q * 4 + 3] = fmaf(h1, wv.w, acc[q * 4 + 3]);
        }
    }
    float oa = b3a, ob = b3b;
#pragma unroll
    for (int i = 0; i < 64; ++i) {
        float h2 = elu(acc[i]);
        oa = fmaf(h2, w3a[i], oa);
        ob = fmaf(h2, w3b[i], ob);
    }
    if (isg) gk_out[idx] = cpx{oa, ob};
    else htab[idx] = oa;
}

// ---------------------------------------------------------------------------
// Kernel 2: one 512-thread block per row.
// fusedS0->A, S1 A->B, S2 B->A(swz3), S3 A->B, spectral+invS0 B->A,
// S1 A->B, S2 B->A(swz3), S3g A->GLOBAL (coalesced).
// ---------------------------------------------------------------------------
__global__ __launch_bounds__(512, 4) void morp_main(
    const float* __restrict__ u, const float* __restrict__ htab,
    const cpx* __restrict__ gk, const cpx* __restrict__ tw,
    float* __restrict__ out) {
    __shared__ __align__(16) cpx bufA[4096];
    __shared__ __align__(16) cpx bufB[4096];
    const int tid = threadIdx.x;
    const int row = blockIdx.x;

    // ---- precomputed swizzled bases (once per thread)
    const int w3c = (tid >> 6) & 7;                           // wave id
    const int s0 = swz(tid);                                  // +512t (imm)
    const int b1i = (tid & 63) + 512 * (tid >> 6);
    const int s1 = b1i ^ ((b1i >> 3) & 7);                    // ^66t
    const int b2i = (tid & 7) + 64 * (tid >> 3);
    const int s2r = b2i ^ (((tid >> 3) & 7) << 1);            // ^9t (read, swz)
    const int s2w = s2r ^ w3c;                                // ^9t (write, swz3)
    const int s3r3 = (8 * tid) ^ (tid & 7) ^ (((tid >> 3) & 7) << 1) ^ w3c;
    const int m3 = (tid >> 6) | (tid & 0x38) | ((tid & 7) << 6);  // involution
    const int s3w = swz(m3);                                  // +512t (imm)
    const int qrev = m3;                                      // digit-reverse
    const int s3g3 = (8 * qrev) ^ (qrev & 7) ^ (((qrev >> 3) & 7) << 1)
                     ^ ((qrev >> 6) & 7);
    const int sm = swz(4096 - tid);                           // mirror: -512c
    const int jb1 = 64 * (tid >> 6);
    const int jb2 = 8 * ((tid >> 6) + 8 * ((tid >> 3) & 7));

    // ---- fused table-lerp + forward stage 0 (DFT8 over t4) -> bufA
    {
        const float2* urow2 = (const float2*)(u + (size_t)row * 8192);
        cpx v[8];
#pragma unroll
        for (int t = 0; t < 8; ++t) {
            const float2 uv = urow2[tid + 512 * t];
            float t0 = fmaf(uv.x, 256.0f, 2048.0f);
            t0 = fminf(fmaxf(t0, 0.0f), 4095.0f);
            const float fi0 = floorf(t0);
            const int i0 = (int)fi0;
            const float h00 = htab[i0], h01 = htab[i0 + 1];
            float t1 = fmaf(uv.y, 256.0f, 2048.0f);
            t1 = fminf(fmaxf(t1, 0.0f), 4095.0f);
            const float fi1 = floorf(t1);
            const int i1 = (int)fi1;
            const float h10 = htab[i1], h11 = htab[i1 + 1];
            v[t] = cpx{fmaf(t0 - fi0, h01 - h00, h00),
                       fmaf(t1 - fi1, h11 - h10, h10)};
        }
        dft8<-1>(v);
        cpx* __restrict__ p = bufA + s0;
#pragma unroll
        for (int t = 0; t < 8; ++t) p[512 * t] = v[t];
    }
    __syncthreads();
    stage1<-1>(bufA, bufB, s1, jb1, tw);
    __syncthreads();
    stage2<-1>(bufB, bufA, s2r, s2w, jb2, tw);
    __syncthreads();
    stage3<-1>(bufA, bufB, s3r3, s3w, m3, tw);
    __syncthreads();

    // ---- fused spectral + inverse stage 0: read bufB (swz), write bufA (swz)
    {
        constexpr float Wr[8] = {1.0f, 0.92387953251128676f, 0.70710678118654752f,
                                 0.38268343236508977f, 0.0f, -0.38268343236508977f,
                                 -0.70710678118654752f, -0.92387953251128676f};
        constexpr float Wi[8] = {0.0f, -0.38268343236508977f, -0.70710678118654752f,
                                 -0.92387953251128676f, -1.0f, -0.92387953251128676f,
                                 -0.70710678118654752f, -0.38268343236508977f};
        const float invn = 1.0f / 4096.0f;
        cpx zres[8];
        cpx w0;
        {
            float ang = -TWO_PI_F * (float)tid / 8192.0f;
            __sincosf(ang, &w0.y, &w0.x);
        }
        const cpx* __restrict__ pk = bufB + s0;
        const int c0mir = (tid == 0) ? 0 : sm;
#pragma unroll
        for (int c = 0; c < 8; ++c) {
            const cpx w = cmul(w0, cpx{Wr[c], Wi[c]});
            const int k = tid + 512 * c;
            const cpx Zk = pk[512 * c];
            const cpx Zc = cconj(bufB[c == 0 ? c0mir : (sm - 512 * c)]);
            const cpx s = cadd(Zk, Zc);
            const cpx d = csub(Zk, Zc);
            const cpx wd = cmul(w, d);
            const cpx huh{0.5f * (s.x + wd.y), 0.5f * (s.y - wd.x)};
            const cpx Zr = cconj(Zc);
            const cpx Zkc = cconj(Zk);
            const cpx s2v = cadd(Zr, Zkc);
            const cpx d2v = csub(Zr, Zkc);
            const cpx wr{-w.x, w.y};
            const cpx wd2 = cmul(wr, d2v);
            const cpx huhr{0.5f * (s2v.x + wd2.y), 0.5f * (s2v.y - wd2.x)};
            const cpx Yk = cmul(gk[k], huh);
            const cpx Yrc = cconj(cmul(gk[4096 - k], huhr));
            const cpx E = cscale(0.5f, cadd(Yk, Yrc));
            const cpx D = cscale(0.5f, csub(Yk, Yrc));
            const cpx O = cmul(cconj(w), D);
            zres[c] = cpx{(E.x - O.y) * invn, (E.y + O.x) * invn};
        }
        dft8<1>(zres);
        cpx* __restrict__ pw = bufA + s0;
#pragma unroll
        for (int c = 0; c < 8; ++c) pw[512 * c] = zres[c];
    }
    __syncthreads();
    stage1<1>(bufA, bufB, s1, jb1, tw);
    __syncthreads();
    stage2<1>(bufB, bufA, s2r, s2w, jb2, tw);
    __syncthreads();

    // ---- inverse S3 with digit-reversed relabeling: read bufA (swz3),
    // twiddle jb = tid (= m3(qrev)), write GLOBAL coalesced at n = tid+512t.
    {
        cpx v[8];
#pragma unroll
        for (int t = 0; t < 8; ++t) v[t] = bufA[s3g3 ^ t];
        if (tid) twid_apply<1>(v, tw, tid);
        dft8<1>(v);
        cpx* orow = (cpx*)(out + (size_t)row * 8192);
#pragma unroll
        for (int t = 0; t < 8; ++t) orow[tid + 512 * t] = v[t];
    }
}

extern "C" void kernel_launch(void* const* d_in, const int* in_sizes, int n_in,
                              void* d_out, int out_size, void* d_ws, size_t ws_size,
                              hipStream_t stream) {
    const float* u   = (const float*)d_in[0];
    const float* kin = (const float*)d_in[1];
    const float* hw1 = (const float*)d_in[2];
    const float* hb1 = (const float*)d_in[3];
    const float* hw2 = (const float*)d_in[4];
    const float* hb2 = (const float*)d_in[5];
    const float* hw3 = (const float*)d_in[6];
    const float* hb3 = (const float*)d_in[7];
    const float* gw1 = (const float*)d_in[8];
    const float* gb1 = (const float*)d_in[9];
    const float* gw2 = (const float*)d_in[10];
    const float* gb2 = (const float*)d_in[11];
    const float* gw3 = (const float*)d_in[12];
    const float* gb3 = (const float*)d_in[13];

    cpx* gk = (cpx*)d_ws;                               // 4097*8 = 32776 B
    float* htab = (float*)((char*)d_ws + 32832);        // 4097*4 = 16388 B
    cpx* twtab = (cpx*)((char*)d_ws + 49280);           // 4096*8 = 32768 B
    tables_kernel<<<50, 256, 0, stream>>>(kin, gw1, gb1, gw2, gb2, gw3, gb3,
                                          hw1, hb1, hw2, hb2, hw3, hb3,
                                          gk, htab, twtab);
    morp_main<<<2048, 512, 0, stream>>>(u, htab, gk, twtab, (float*)d_out);
}

// Round 15
// 77.492 us; speedup vs baseline: 1.2888x; 1.2888x over previous
//
#include <hip/hip_runtime.h>
#include <hip/hip_bf16.h>
#include <cstddef>

// ---------------------------------------------------------------------------
// MORP: Lu = irfft( g(k) * rfft( h(u) ) ), h/g tiny MLPs (1->64->64->{1,2}, ELU)
// B=2048 rows, N=8192, M=4097, W=64.
// Round 15 = Round 13 (best: 59.5us, computed twiddles, copy-out phase) with
// ONE change: the spectral phase is C-bilinear, Zi[k] = A[k]*Z[k] +
// B[k]*conj(Z[4096-k]); A,B (invn folded) precomputed by ab_kernel via basis
// evaluation of the exact r13 float code. morp_main spectral body becomes
// one coalesced float4 load + 2 cmul + 1 cadd. Round-14's per-lane twiddle
// TABLE is ABANDONED (divergent gathers: VALUBusy 53->40, dur 59->80).
// Out-of-place FFT only (in-place BANNED). Register arrays fully unrolled.
// ---------------------------------------------------------------------------

#define TWO_PI_F 6.28318530717958647693f

struct __align__(8) cpx { float x, y; };

__device__ __forceinline__ cpx cmul(cpx a, cpx b) {
    return cpx{fmaf(a.x, b.x, -a.y * b.y), fmaf(a.x, b.y, a.y * b.x)};
}
__device__ __forceinline__ cpx cadd(cpx a, cpx b) { return cpx{a.x + b.x, a.y + b.y}; }
__device__ __forceinline__ cpx csub(cpx a, cpx b) { return cpx{a.x - b.x, a.y - b.y}; }
__device__ __forceinline__ cpx cscale(float s, cpx a) { return cpx{s * a.x, s * a.y}; }
__device__ __forceinline__ cpx cconj(cpx a) { return cpx{a.x, -a.y}; }
template <int S>
__device__ __forceinline__ cpx crot(cpx z) {   // multiply by S<0 ? -i : +i
    return (S < 0) ? cpx{z.y, -z.x} : cpx{-z.y, z.x};
}

__device__ __forceinline__ float elu(float x) {
    return x > 0.0f ? x : (__expf(x) - 1.0f);
}

// LDS index swizzle (bits 0-8 only; bits >=9 pass through untouched).
__device__ __forceinline__ int swz(int i) {
    return i ^ ((i >> 3) & 7) ^ (((i >> 6) & 7) << 1);
}

// ---------------------------------------------------------------------------
// In-register 4/8-point DFT (natural order), sign S (-1 fwd, +1 inv).
// ---------------------------------------------------------------------------
template <int S>
__device__ __forceinline__ void dft4(cpx& x0, cpx& x1, cpx& x2, cpx& x3) {
    cpx e0 = cadd(x0, x2), e1 = csub(x0, x2);
    cpx o0 = cadd(x1, x3), o1 = crot<S>(csub(x1, x3));
    x0 = cadd(e0, o0);
    x1 = cadd(e1, o1);
    x2 = csub(e0, o0);
    x3 = csub(e1, o1);
}

template <int S>
__device__ __forceinline__ void dft8(cpx v[8]) {
    constexpr float r = 0.70710678118654752f;
    cpx E0 = v[0], E1 = v[2], E2 = v[4], E3 = v[6];
    cpx O0 = v[1], O1 = v[3], O2 = v[5], O3 = v[7];
    dft4<S>(E0, E1, E2, E3);
    dft4<S>(O0, O1, O2, O3);
    O1 = (S < 0) ? cpx{r * (O1.x + O1.y), r * (O1.y - O1.x)}
                 : cpx{r * (O1.x - O1.y), r * (O1.x + O1.y)};
    O2 = crot<S>(O2);
    O3 = (S < 0) ? cpx{r * (O3.y - O3.x), -r * (O3.x + O3.y)}
                 : cpx{-r * (O3.x + O3.y), r * (O3.x - O3.y)};
    v[0] = cadd(E0, O0);
    v[1] = cadd(E1, O1);
    v[2] = cadd(E2, O2);
    v[3] = cadd(E3, O3);
    v[4] = csub(E0, O0);
    v[5] = csub(E1, O1);
    v[6] = csub(E2, O2);
    v[7] = csub(E3, O3);
}

// Apply w^t, t=1..7, with w = cis(ang); depth-3 product tree.
template <int S>
__device__ __forceinline__ void twiddle8(cpx v[8], float ang) {
    cpx w;
    __sincosf(ang, &w.y, &w.x);
    const cpx t2 = cmul(w, w);
    const cpx t3 = cmul(t2, w);
    const cpx t4 = cmul(t2, t2);
    const cpx t5 = cmul(t4, w);
    const cpx t6 = cmul(t4, t2);
    const cpx t7 = cmul(t4, t3);
    v[1] = cmul(v[1], w);
    v[2] = cmul(v[2], t2);
    v[3] = cmul(v[3], t3);
    v[4] = cmul(v[4], t4);
    v[5] = cmul(v[5], t5);
    v[6] = cmul(v[6], t6);
    v[7] = cmul(v[7], t7);
}

// ---------------------------------------------------------------------------
// Radix-8 stages with precomputed swizzled bases (identical to round 13).
// ---------------------------------------------------------------------------
template <int S>
__device__ __forceinline__ void stage1(const cpx* __restrict__ src,
                                       cpx* __restrict__ dst, int s1, int k4) {
    cpx v[8];
#pragma unroll
    for (int t = 0; t < 8; ++t) v[t] = src[s1 ^ (66 * t)];
    twiddle8<S>(v, (float)S * (TWO_PI_F / 64.0f) * (float)k4);
    dft8<S>(v);
#pragma unroll
    for (int t = 0; t < 8; ++t) dst[s1 ^ (66 * t)] = v[t];
}

template <int S>
__device__ __forceinline__ void stage2(const cpx* __restrict__ src,
                                       cpx* __restrict__ dst, int s2, int m2) {
    cpx v[8];
#pragma unroll
    for (int t = 0; t < 8; ++t) v[t] = src[s2 ^ (9 * t)];
    twiddle8<S>(v, (float)S * (TWO_PI_F / 512.0f) * (float)m2);
    dft8<S>(v);
#pragma unroll
    for (int t = 0; t < 8; ++t) dst[s2 ^ (9 * t)] = v[t];
}

template <int S>
__device__ __forceinline__ void stage3(const cpx* __restrict__ src,
                                       cpx* __restrict__ dst, int s3r, int s3w,
                                       int m3) {
    cpx v[8];
#pragma unroll
    for (int t = 0; t < 8; ++t) v[t] = src[s3r ^ t];
    twiddle8<S>(v, (float)S * (TWO_PI_F / 4096.0f) * (float)m3);
    dft8<S>(v);
    cpx* __restrict__ pw = dst + s3w;
#pragma unroll
    for (int t = 0; t < 8; ++t) pw[512 * t] = v[t];
}

// ---------------------------------------------------------------------------
// Kernel 1: blocks 0..16 -> gk[k]; blocks 17..33 -> htab (exact fp32 h).
// ---------------------------------------------------------------------------
__global__ __launch_bounds__(256, 2) void tables_kernel(
    const float* __restrict__ kin,
    const float* __restrict__ gw1, const float* __restrict__ gb1,
    const float* __restrict__ gw2, const float* __restrict__ gb2,
    const float* __restrict__ gw3, const float* __restrict__ gb3,
    const float* __restrict__ hw1, const float* __restrict__ hb1,
    const float* __restrict__ hw2, const float* __restrict__ hb2,
    const float* __restrict__ hw3, const float* __restrict__ hb3,
    cpx* __restrict__ gk_out, float* __restrict__ htab) {
    __shared__ __align__(16) float w2[4096];
    __shared__ float w1[64], b1[64], b2[64], w3a[64], w3b[64];
    __shared__ float b3a, b3b;
    const int tid = threadIdx.x;
    const bool isg = blockIdx.x < 17;
    const float* W1 = isg ? gw1 : hw1;
    const float* B1 = isg ? gb1 : hb1;
    const float* W2 = isg ? gw2 : hw2;
    const float* B2 = isg ? gb2 : hb2;
    for (int i = tid; i < 4096; i += 256) w2[i] = W2[i];
    if (tid < 64) {
        w1[tid] = W1[tid];
        b1[tid] = B1[tid];
        b2[tid] = B2[tid];
        if (isg) {
            w3a[tid] = gw3[tid * 2 + 0];
            w3b[tid] = gw3[tid * 2 + 1];
        } else {
            w3a[tid] = hw3[tid];
            w3b[tid] = 0.0f;
        }
    }
    if (tid == 0) {
        b3a = isg ? gb3[0] : hb3[0];
        b3b = isg ? gb3[1] : 0.0f;
    }
    __syncthreads();
    const int idx = (isg ? blockIdx.x : blockIdx.x - 17) * 256 + tid;
    if (idx >= 4097) return;
    const float x = isg ? kin[idx] : (-8.0f + (float)idx * (16.0f / 4096.0f));
    float acc[64];
#pragma unroll
    for (int i = 0; i < 64; ++i) acc[i] = b2[i];
#pragma unroll 2
    for (int j = 0; j < 64; ++j) {
        float h1 = elu(fmaf(x, w1[j], b1[j]));
        const float4* wr = (const float4*)&w2[j * 64];
#pragma unroll
        for (int q = 0; q < 16; ++q) {
            float4 wv = wr[q];
            acc[q * 4 + 0] = fmaf(h1, wv.x, acc[q * 4 + 0]);
            acc[q * 4 + 1] = fmaf(h1, wv.y, acc[q * 4 + 1]);
            acc[q * 4 + 2] = fmaf(h1, wv.z, acc[q * 4 + 2]);
            acc[q * 4 + 3] = fmaf(h1, wv.w, acc[q * 4 + 3]);
        }
    }
    float oa = b3a, ob = b3b;
#pragma unroll
    for (int i = 0; i < 64; ++i) {
        float h2 = elu(acc[i]);
        oa = fmaf(h2, w3a[i], oa);
        ob = fmaf(h2, w3b[i], ob);
    }
    if (isg) gk_out[idx] = cpx{oa, ob};
    else htab[idx] = oa;
}

// ---------------------------------------------------------------------------
// Kernel 1b: ab[k] for k=0..4095 — basis evaluation of the spectral map.
// Zi[k] = A*Zk + B*conj(Z[4096-k]), invn folded in. Exact r13 float code.
// ---------------------------------------------------------------------------
__device__ __forceinline__ cpx spectral_eval(cpx Zk, cpx Zc, cpx w,
                                             cpx gkk, cpx gkm) {
    const cpx s = cadd(Zk, Zc);
    const cpx d = csub(Zk, Zc);
    const cpx wd = cmul(w, d);
    const cpx huh{0.5f * (s.x + wd.y), 0.5f * (s.y - wd.x)};
    const cpx Zr = cconj(Zc);
    const cpx Zkc = cconj(Zk);
    const cpx s2v = cadd(Zr, Zkc);
    const cpx d2v = csub(Zr, Zkc);
    const cpx wr{-w.x, w.y};
    const cpx wd2 = cmul(wr, d2v);
    const cpx huhr{0.5f * (s2v.x + wd2.y), 0.5f * (s2v.y - wd2.x)};
    const cpx Yk = cmul(gkk, huh);
    const cpx Yrc = cconj(cmul(gkm, huhr));
    const cpx E = cscale(0.5f, cadd(Yk, Yrc));
    const cpx D = cscale(0.5f, csub(Yk, Yrc));
    const cpx O = cmul(cconj(w), D);
    return cpx{E.x - O.y, E.y + O.x};
}

__global__ __launch_bounds__(256, 2) void ab_kernel(
    const cpx* __restrict__ gk, float4* __restrict__ ab) {
    const int k = blockIdx.x * 256 + threadIdx.x;   // 0..4095
    const float invn = 1.0f / 4096.0f;
    cpx w;
    {
        float ang = -TWO_PI_F * (float)k / 8192.0f;
        __sincosf(ang, &w.y, &w.x);
    }
    const cpx gkk = gk[k];
    const cpx gkm = gk[4096 - k];
    const cpx A = spectral_eval(cpx{1.0f, 0.0f}, cpx{0.0f, 0.0f}, w, gkk, gkm);
    const cpx B = spectral_eval(cpx{0.0f, 0.0f}, cpx{1.0f, 0.0f}, w, gkk, gkm);
    ab[k] = float4{A.x * invn, A.y * invn, B.x * invn, B.y * invn};
}

// ---------------------------------------------------------------------------
// Kernel 2: one 512-thread block per row (r13 structure).
// Ping-pong: fusedS0->A, S1 A->B, S2 B->A, S3 A->B, spectral+invS0 B->A,
//            S1 A->B, S2 B->A, S3 A->B, copyout B.
// ---------------------------------------------------------------------------
__global__ __launch_bounds__(512, 4) void morp_main(
    const float* __restrict__ u, const float* __restrict__ htab,
    const float4* __restrict__ ab, float* __restrict__ out) {
    __shared__ __align__(16) cpx bufA[4096];
    __shared__ __align__(16) cpx bufB[4096];
    const int tid = threadIdx.x;
    const int row = blockIdx.x;

    // ---- precomputed swizzled bases (once per thread)
    const int s0 = swz(tid);                                  // +512t (imm)
    const int b1 = (tid & 63) + 512 * (tid >> 6);
    const int s1 = b1 ^ ((b1 >> 3) & 7);                      // ^66t
    const int b2 = (tid & 7) + 64 * (tid >> 3);
    const int s2 = b2 ^ (((tid >> 3) & 7) << 1);              // ^9t
    const int b3 = 8 * (tid & 7) + 64 * (tid >> 3);
    const int s3r = b3 ^ (tid & 7) ^ (((tid >> 3) & 7) << 1); // ^t
    const int m3 = (tid >> 6) + 8 * ((tid >> 3) & 7) + 64 * (tid & 7);
    const int s3w = swz(m3);                                  // +512t (imm)
    const int sm = swz(4096 - tid);                           // mirror: -512c
    const int k4 = tid >> 6;
    const int m2 = (tid >> 6) + 8 * ((tid >> 3) & 7);

    // ---- fused table-lerp + forward stage 0 (DFT8 over t4) -> bufA
    {
        const float2* urow2 = (const float2*)(u + (size_t)row * 8192);
        cpx v[8];
#pragma unroll
        for (int t = 0; t < 8; ++t) {
            const float2 uv = urow2[tid + 512 * t];
            float t0 = fmaf(uv.x, 256.0f, 2048.0f);
            t0 = fminf(fmaxf(t0, 0.0f), 4095.0f);
            const float fi0 = floorf(t0);
            const int i0 = (int)fi0;
            const float h00 = htab[i0], h01 = htab[i0 + 1];
            float t1 = fmaf(uv.y, 256.0f, 2048.0f);
            t1 = fminf(fmaxf(t1, 0.0f), 4095.0f);
            const float fi1 = floorf(t1);
            const int i1 = (int)fi1;
            const float h10 = htab[i1], h11 = htab[i1 + 1];
            v[t] = cpx{fmaf(t0 - fi0, h01 - h00, h00),
                       fmaf(t1 - fi1, h11 - h10, h10)};
        }
        dft8<-1>(v);
        cpx* __restrict__ p = bufA + s0;
#pragma unroll
        for (int t = 0; t < 8; ++t) p[512 * t] = v[t];
    }
    __syncthreads();
    stage1<-1>(bufA, bufB, s1, k4);
    __syncthreads();
    stage2<-1>(bufB, bufA, s2, m2);
    __syncthreads();
    stage3<-1>(bufA, bufB, s3r, s3w, m3);
    __syncthreads();

    // ---- fused spectral (bilinear A/B form) + inverse stage 0: B -> A
    {
        cpx zres[8];
        const cpx* __restrict__ pk = bufB + s0;
        const int c0mir = (tid == 0) ? 0 : sm;
#pragma unroll
        for (int c = 0; c < 8; ++c) {
            const int k = tid + 512 * c;
            const float4 abv = ab[k];
            const cpx Zk = pk[512 * c];
            const cpx Zc = cconj(bufB[c == 0 ? c0mir : (sm - 512 * c)]);
            const cpx az = cmul(cpx{abv.x, abv.y}, Zk);
            const cpx bz = cmul(cpx{abv.z, abv.w}, Zc);
            zres[c] = cadd(az, bz);
        }
        dft8<1>(zres);
        cpx* __restrict__ pw = bufA + s0;
#pragma unroll
        for (int c = 0; c < 8; ++c) pw[512 * c] = zres[c];
    }
    __syncthreads();
    stage1<1>(bufA, bufB, s1, k4);
    __syncthreads();
    stage2<1>(bufB, bufA, s2, m2);
    __syncthreads();
    stage3<1>(bufA, bufB, s3r, s3w, m3);
    __syncthreads();

    // ---- copy out (scale folded into A/B)
    {
        cpx* orow = (cpx*)(out + (size_t)row * 8192);
        const cpx* __restrict__ p = bufB + s0;
#pragma unroll
        for (int c = 0; c < 8; ++c) orow[tid + 512 * c] = p[512 * c];
    }
}

extern "C" void kernel_launch(void* const* d_in, const int* in_sizes, int n_in,
                              void* d_out, int out_size, void* d_ws, size_t ws_size,
                              hipStream_t stream) {
    const float* u   = (const float*)d_in[0];
    const float* kin = (const float*)d_in[1];
    const float* hw1 = (const float*)d_in[2];
    const float* hb1 = (const float*)d_in[3];
    const float* hw2 = (const float*)d_in[4];
    const float* hb2 = (const float*)d_in[5];
    const float* hw3 = (const float*)d_in[6];
    const float* hb3 = (const float*)d_in[7];
    const float* gw1 = (const float*)d_in[8];
    const float* gb1 = (const float*)d_in[9];
    const float* gw2 = (const float*)d_in[10];
    const float* gb2 = (const float*)d_in[11];
    const float* gw3 = (const float*)d_in[12];
    const float* gb3 = (const float*)d_in[13];

    cpx* gk = (cpx*)d_ws;                               // 4097*8 = 32776 B
    float* htab = (float*)((char*)d_ws + 32832);        // 4097*4 = 16388 B
    float4* ab = (float4*)((char*)d_ws + 49280);        // 4096*16 = 65536 B
    tables_kernel<<<34, 256, 0, stream>>>(kin, gw1, gb1, gw2, gb2, gw3, gb3,
                                          hw1, hb1, hw2, hb2, hw3, hb3,
                                          gk, htab);
    ab_kernel<<<16, 256, 0, stream>>>(gk, ab);
    morp_main<<<2048, 512, 0, stream>>>(u, htab, ab, (float*)d_out);
}

// Round 16
// 76.289 us; speedup vs baseline: 1.3091x; 1.0158x over previous
//
#include <hip/hip_runtime.h>
#include <hip/hip_bf16.h>
#include <cstddef>

// ---------------------------------------------------------------------------
// MORP: Lu = irfft( g(k) * rfft( h(u) ) ), h/g tiny MLPs (1->64->64->{1,2}, ELU)
// B=2048 rows, N=8192, M=4097, W=64.
// Round 16 = Round 15 (bilinear A/B spectral, 52us) + r14's GOOD half alone:
// inverse S3 relabeled by the involution q = m3(tid) so thread tid's twiddle
// index is tid and its outputs write GLOBAL coalesced at n = tid+512t.
// Deletes inv-S3 LDS writes + entire copy-out + 1 barrier (16 LDS ops/thread).
// Computed twiddles everywhere (r14's per-lane twiddle TABLE stays ABANDONED).
// Inverse S2-write/S3-read generation uses swz3 = swz ^ ((i>>9)&7): wave-
// uniform on the S2 write, spreads the relabeled S3 read 8-way -> 4-way.
// Forward path byte-identical to r15. In-place FFT remains BANNED.
// ---------------------------------------------------------------------------

#define TWO_PI_F 6.28318530717958647693f

struct __align__(8) cpx { float x, y; };

__device__ __forceinline__ cpx cmul(cpx a, cpx b) {
    return cpx{fmaf(a.x, b.x, -a.y * b.y), fmaf(a.x, b.y, a.y * b.x)};
}
__device__ __forceinline__ cpx cadd(cpx a, cpx b) { return cpx{a.x + b.x, a.y + b.y}; }
__device__ __forceinline__ cpx csub(cpx a, cpx b) { return cpx{a.x - b.x, a.y - b.y}; }
__device__ __forceinline__ cpx cscale(float s, cpx a) { return cpx{s * a.x, s * a.y}; }
__device__ __forceinline__ cpx cconj(cpx a) { return cpx{a.x, -a.y}; }
template <int S>
__device__ __forceinline__ cpx crot(cpx z) {   // multiply by S<0 ? -i : +i
    return (S < 0) ? cpx{z.y, -z.x} : cpx{-z.y, z.x};
}

__device__ __forceinline__ float elu(float x) {
    return x > 0.0f ? x : (__expf(x) - 1.0f);
}

// LDS index swizzle (bits 0-8 only; bits >=9 pass through untouched).
__device__ __forceinline__ int swz(int i) {
    return i ^ ((i >> 3) & 7) ^ (((i >> 6) & 7) << 1);
}

// ---------------------------------------------------------------------------
// In-register 4/8-point DFT (natural order), sign S (-1 fwd, +1 inv).
// ---------------------------------------------------------------------------
template <int S>
__device__ __forceinline__ void dft4(cpx& x0, cpx& x1, cpx& x2, cpx& x3) {
    cpx e0 = cadd(x0, x2), e1 = csub(x0, x2);
    cpx o0 = cadd(x1, x3), o1 = crot<S>(csub(x1, x3));
    x0 = cadd(e0, o0);
    x1 = cadd(e1, o1);
    x2 = csub(e0, o0);
    x3 = csub(e1, o1);
}

template <int S>
__device__ __forceinline__ void dft8(cpx v[8]) {
    constexpr float r = 0.70710678118654752f;
    cpx E0 = v[0], E1 = v[2], E2 = v[4], E3 = v[6];
    cpx O0 = v[1], O1 = v[3], O2 = v[5], O3 = v[7];
    dft4<S>(E0, E1, E2, E3);
    dft4<S>(O0, O1, O2, O3);
    O1 = (S < 0) ? cpx{r * (O1.x + O1.y), r * (O1.y - O1.x)}
                 : cpx{r * (O1.x - O1.y), r * (O1.x + O1.y)};
    O2 = crot<S>(O2);
    O3 = (S < 0) ? cpx{r * (O3.y - O3.x), -r * (O3.x + O3.y)}
                 : cpx{-r * (O3.x + O3.y), r * (O3.x - O3.y)};
    v[0] = cadd(E0, O0);
    v[1] = cadd(E1, O1);
    v[2] = cadd(E2, O2);
    v[3] = cadd(E3, O3);
    v[4] = csub(E0, O0);
    v[5] = csub(E1, O1);
    v[6] = csub(E2, O2);
    v[7] = csub(E3, O3);
}

// Apply w^t, t=1..7, with w = cis(ang); depth-3 product tree.
template <int S>
__device__ __forceinline__ void twiddle8(cpx v[8], float ang) {
    cpx w;
    __sincosf(ang, &w.y, &w.x);
    const cpx t2 = cmul(w, w);
    const cpx t3 = cmul(t2, w);
    const cpx t4 = cmul(t2, t2);
    const cpx t5 = cmul(t4, w);
    const cpx t6 = cmul(t4, t2);
    const cpx t7 = cmul(t4, t3);
    v[1] = cmul(v[1], w);
    v[2] = cmul(v[2], t2);
    v[3] = cmul(v[3], t3);
    v[4] = cmul(v[4], t4);
    v[5] = cmul(v[5], t5);
    v[6] = cmul(v[6], t6);
    v[7] = cmul(v[7], t7);
}

// ---------------------------------------------------------------------------
// Radix-8 stages with precomputed swizzled bases.
// ---------------------------------------------------------------------------
template <int S>
__device__ __forceinline__ void stage1(const cpx* __restrict__ src,
                                       cpx* __restrict__ dst, int s1, int k4) {
    cpx v[8];
#pragma unroll
    for (int t = 0; t < 8; ++t) v[t] = src[s1 ^ (66 * t)];
    twiddle8<S>(v, (float)S * (TWO_PI_F / 64.0f) * (float)k4);
    dft8<S>(v);
#pragma unroll
    for (int t = 0; t < 8; ++t) dst[s1 ^ (66 * t)] = v[t];
}

// read base s2r, write base s2w (equal on the forward path; ^waveid inverse)
template <int S>
__device__ __forceinline__ void stage2(const cpx* __restrict__ src,
                                       cpx* __restrict__ dst, int s2r, int s2w,
                                       int m2) {
    cpx v[8];
#pragma unroll
    for (int t = 0; t < 8; ++t) v[t] = src[s2r ^ (9 * t)];
    twiddle8<S>(v, (float)S * (TWO_PI_F / 512.0f) * (float)m2);
    dft8<S>(v);
#pragma unroll
    for (int t = 0; t < 8; ++t) dst[s2w ^ (9 * t)] = v[t];
}

template <int S>
__device__ __forceinline__ void stage3(const cpx* __restrict__ src,
                                       cpx* __restrict__ dst, int s3r, int s3w,
                                       int m3) {
    cpx v[8];
#pragma unroll
    for (int t = 0; t < 8; ++t) v[t] = src[s3r ^ t];
    twiddle8<S>(v, (float)S * (TWO_PI_F / 4096.0f) * (float)m3);
    dft8<S>(v);
    cpx* __restrict__ pw = dst + s3w;
#pragma unroll
    for (int t = 0; t < 8; ++t) pw[512 * t] = v[t];
}

// ---------------------------------------------------------------------------
// Kernel 1: blocks 0..16 -> gk[k]; blocks 17..33 -> htab (exact fp32 h).
// ---------------------------------------------------------------------------
__global__ __launch_bounds__(256, 2) void tables_kernel(
    const float* __restrict__ kin,
    const float* __restrict__ gw1, const float* __restrict__ gb1,
    const float* __restrict__ gw2, const float* __restrict__ gb2,
    const float* __restrict__ gw3, const float* __restrict__ gb3,
    const float* __restrict__ hw1, const float* __restrict__ hb1,
    const float* __restrict__ hw2, const float* __restrict__ hb2,
    const float* __restrict__ hw3, const float* __restrict__ hb3,
    cpx* __restrict__ gk_out, float* __restrict__ htab) {
    __shared__ __align__(16) float w2[4096];
    __shared__ float w1[64], b1[64], b2[64], w3a[64], w3b[64];
    __shared__ float b3a, b3b;
    const int tid = threadIdx.x;
    const bool isg = blockIdx.x < 17;
    const float* W1 = isg ? gw1 : hw1;
    const float* B1 = isg ? gb1 : hb1;
    const float* W2 = isg ? gw2 : hw2;
    const float* B2 = isg ? gb2 : hb2;
    for (int i = tid; i < 4096; i += 256) w2[i] = W2[i];
    if (tid < 64) {
        w1[tid] = W1[tid];
        b1[tid] = B1[tid];
        b2[tid] = B2[tid];
        if (isg) {
            w3a[tid] = gw3[tid * 2 + 0];
            w3b[tid] = gw3[tid * 2 + 1];
        } else {
            w3a[tid] = hw3[tid];
            w3b[tid] = 0.0f;
        }
    }
    if (tid == 0) {
        b3a = isg ? gb3[0] : hb3[0];
        b3b = isg ? gb3[1] : 0.0f;
    }
    __syncthreads();
    const int idx = (isg ? blockIdx.x : blockIdx.x - 17) * 256 + tid;
    if (idx >= 4097) return;
    const float x = isg ? kin[idx] : (-8.0f + (float)idx * (16.0f / 4096.0f));
    float acc[64];
#pragma unroll
    for (int i = 0; i < 64; ++i) acc[i] = b2[i];
#pragma unroll 2
    for (int j = 0; j < 64; ++j) {
        float h1 = elu(fmaf(x, w1[j], b1[j]));
        const float4* wr = (const float4*)&w2[j * 64];
#pragma unroll
        for (int q = 0; q < 16; ++q) {
            float4 wv = wr[q];
            acc[q * 4 + 0] = fmaf(h1, wv.x, acc[q * 4 + 0]);
            acc[q * 4 + 1] = fmaf(h1, wv.y, acc[q * 4 + 1]);
            acc[q * 4 + 2] = fmaf(h1, wv.z, acc[q * 4 + 2]);
            acc[q * 4 + 3] = fmaf(h1, wv.w, acc[q * 4 + 3]);
        }
    }
    float oa = b3a, ob = b3b;
#pragma unroll
    for (int i = 0; i < 64; ++i) {
        float h2 = elu(acc[i]);
        oa = fmaf(h2, w3a[i], oa);
        ob = fmaf(h2, w3b[i], ob);
    }
    if (isg) gk_out[idx] = cpx{oa, ob};
    else htab[idx] = oa;
}

// ---------------------------------------------------------------------------
// Kernel 1b: ab[k] for k=0..4095 — basis evaluation of the spectral map.
// Zi[k] = A*Zk + B*conj(Z[4096-k]), invn folded in.
// ---------------------------------------------------------------------------
__device__ __forceinline__ cpx spectral_eval(cpx Zk, cpx Zc, cpx w,
                                             cpx gkk, cpx gkm) {
    const cpx s = cadd(Zk, Zc);
    const cpx d = csub(Zk, Zc);
    const cpx wd = cmul(w, d);
    const cpx huh{0.5f * (s.x + wd.y), 0.5f * (s.y - wd.x)};
    const cpx Zr = cconj(Zc);
    const cpx Zkc = cconj(Zk);
    const cpx s2v = cadd(Zr, Zkc);
    const cpx d2v = csub(Zr, Zkc);
    const cpx wr{-w.x, w.y};
    const cpx wd2 = cmul(wr, d2v);
    const cpx huhr{0.5f * (s2v.x + wd2.y), 0.5f * (s2v.y - wd2.x)};
    const cpx Yk = cmul(gkk, huh);
    const cpx Yrc = cconj(cmul(gkm, huhr));
    const cpx E = cscale(0.5f, cadd(Yk, Yrc));
    const cpx D = cscale(0.5f, csub(Yk, Yrc));
    const cpx O = cmul(cconj(w), D);
    return cpx{E.x - O.y, E.y + O.x};
}

__global__ __launch_bounds__(256, 2) void ab_kernel(
    const cpx* __restrict__ gk, float4* __restrict__ ab) {
    const int k = blockIdx.x * 256 + threadIdx.x;   // 0..4095
    const float invn = 1.0f / 4096.0f;
    cpx w;
    {
        float ang = -TWO_PI_F * (float)k / 8192.0f;
        __sincosf(ang, &w.y, &w.x);
    }
    const cpx gkk = gk[k];
    const cpx gkm = gk[4096 - k];
    const cpx A = spectral_eval(cpx{1.0f, 0.0f}, cpx{0.0f, 0.0f}, w, gkk, gkm);
    const cpx B = spectral_eval(cpx{0.0f, 0.0f}, cpx{1.0f, 0.0f}, w, gkk, gkm);
    ab[k] = float4{A.x * invn, A.y * invn, B.x * invn, B.y * invn};
}

// ---------------------------------------------------------------------------
// Kernel 2: one 512-thread block per row.
// fusedS0->A, S1 A->B, S2 B->A, S3 A->B, spectral+invS0 B->A,
// S1 A->B, S2 B->A(swz3), S3g A->GLOBAL coalesced (relabeled).
// ---------------------------------------------------------------------------
__global__ __launch_bounds__(512, 4) void morp_main(
    const float* __restrict__ u, const float* __restrict__ htab,
    const float4* __restrict__ ab, float* __restrict__ out) {
    __shared__ __align__(16) cpx bufA[4096];
    __shared__ __align__(16) cpx bufB[4096];
    const int tid = threadIdx.x;
    const int row = blockIdx.x;

    // ---- precomputed swizzled bases (once per thread)
    const int w3c = (tid >> 6) & 7;                           // wave id
    const int s0 = swz(tid);                                  // +512t (imm)
    const int b1 = (tid & 63) + 512 * (tid >> 6);
    const int s1 = b1 ^ ((b1 >> 3) & 7);                      // ^66t
    const int b2 = (tid & 7) + 64 * (tid >> 3);
    const int s2 = b2 ^ (((tid >> 3) & 7) << 1);              // ^9t
    const int b3 = 8 * (tid & 7) + 64 * (tid >> 3);
    const int s3r = b3 ^ (tid & 7) ^ (((tid >> 3) & 7) << 1); // ^t
    const int m3 = (tid >> 6) + 8 * ((tid >> 3) & 7) + 64 * (tid & 7);
    const int s3w = swz(m3);                                  // +512t (imm)
    // relabeled inverse-S3: thread tid runs butterfly q = m3(tid) (involution)
    const int s3g3 = (8 * m3) ^ (m3 & 7) ^ (((m3 >> 3) & 7) << 1)
                     ^ ((m3 >> 6) & 7);                       // swz3 read, ^t
    const int sm = swz(4096 - tid);                           // mirror: -512c
    const int k4 = tid >> 6;
    const int m2 = (tid >> 6) + 8 * ((tid >> 3) & 7);

    // ---- fused table-lerp + forward stage 0 (DFT8 over t4) -> bufA
    {
        const float2* urow2 = (const float2*)(u + (size_t)row * 8192);
        cpx v[8];
#pragma unroll
        for (int t = 0; t < 8; ++t) {
            const float2 uv = urow2[tid + 512 * t];
            float t0 = fmaf(uv.x, 256.0f, 2048.0f);
            t0 = fminf(fmaxf(t0, 0.0f), 4095.0f);
            const float fi0 = floorf(t0);
            const int i0 = (int)fi0;
            const float h00 = htab[i0], h01 = htab[i0 + 1];
            float t1 = fmaf(uv.y, 256.0f, 2048.0f);
            t1 = fminf(fmaxf(t1, 0.0f), 4095.0f);
            const float fi1 = floorf(t1);
            const int i1 = (int)fi1;
            const float h10 = htab[i1], h11 = htab[i1 + 1];
            v[t] = cpx{fmaf(t0 - fi0, h01 - h00, h00),
                       fmaf(t1 - fi1, h11 - h10, h10)};
        }
        dft8<-1>(v);
        cpx* __restrict__ p = bufA + s0;
#pragma unroll
        for (int t = 0; t < 8; ++t) p[512 * t] = v[t];
    }
    __syncthreads();
    stage1<-1>(bufA, bufB, s1, k4);
    __syncthreads();
    stage2<-1>(bufB, bufA, s2, s2, m2);
    __syncthreads();
    stage3<-1>(bufA, bufB, s3r, s3w, m3);
    __syncthreads();

    // ---- fused spectral (bilinear A/B form) + inverse stage 0: B -> A
    {
        cpx zres[8];
        const cpx* __restrict__ pk = bufB + s0;
        const int c0mir = (tid == 0) ? 0 : sm;
#pragma unroll
        for (int c = 0; c < 8; ++c) {
            const int k = tid + 512 * c;
            const float4 abv = ab[k];
            const cpx Zk = pk[512 * c];
            const cpx Zc = cconj(bufB[c == 0 ? c0mir : (sm - 512 * c)]);
            const cpx az = cmul(cpx{abv.x, abv.y}, Zk);
            const cpx bz = cmul(cpx{abv.z, abv.w}, Zc);
            zres[c] = cadd(az, bz);
        }
        dft8<1>(zres);
        cpx* __restrict__ pw = bufA + s0;
#pragma unroll
        for (int c = 0; c < 8; ++c) pw[512 * c] = zres[c];
    }
    __syncthreads();
    stage1<1>(bufA, bufB, s1, k4);
    __syncthreads();
    stage2<1>(bufB, bufA, s2, s2 ^ w3c, m2);   // write generation in swz3
    __syncthreads();

    // ---- inverse S3, relabeled q = m3(tid): read bufA (swz3), twiddle index
    // m3(q) = tid, write GLOBAL coalesced at n = tid + 512t. No copy-out.
    {
        cpx v[8];
#pragma unroll
        for (int t = 0; t < 8; ++t) v[t] = bufA[s3g3 ^ t];
        twiddle8<1>(v, (TWO_PI_F / 4096.0f) * (float)tid);
        dft8<1>(v);
        cpx* orow = (cpx*)(out + (size_t)row * 8192);
#pragma unroll
        for (int t = 0; t < 8; ++t) orow[tid + 512 * t] = v[t];
    }
}

extern "C" void kernel_launch(void* const* d_in, const int* in_sizes, int n_in,
                              void* d_out, int out_size, void* d_ws, size_t ws_size,
                              hipStream_t stream) {
    const float* u   = (const float*)d_in[0];
    const float* kin = (const float*)d_in[1];
    const float* hw1 = (const float*)d_in[2];
    const float* hb1 = (const float*)d_in[3];
    const float* hw2 = (const float*)d_in[4];
    const float* hb2 = (const float*)d_in[5];
    const float* hw3 = (const float*)d_in[6];
    const float* hb3 = (const float*)d_in[7];
    const float* gw1 = (const float*)d_in[8];
    const float* gb1 = (const float*)d_in[9];
    const float* gw2 = (const float*)d_in[10];
    const float* gb2 = (const float*)d_in[11];
    const float* gw3 = (const float*)d_in[12];
    const float* gb3 = (const float*)d_in[13];

    cpx* gk = (cpx*)d_ws;                               // 4097*8 = 32776 B
    float* htab = (float*)((char*)d_ws + 32832);        // 4097*4 = 16388 B
    float4* ab = (float4*)((char*)d_ws + 49280);        // 4096*16 = 65536 B
    tables_kernel<<<34, 256, 0, stream>>>(kin, gw1, gb1, gw2, gb2, gw3, gb3,
                                          hw1, hb1, hw2, hb2, hw3, hb3,
                                          gk, htab);
    ab_kernel<<<16, 256, 0, stream>>>(gk, ab);
    morp_main<<<2048, 512, 0, stream>>>(u, htab, ab, (float*)d_out);
}